// Round 5
// baseline (179.205 us; speedup 1.0000x reference)
//
#include <hip/hip_runtime.h>
#include <math.h>

// ---------- types ----------
typedef __bf16 bf16_t;
typedef __bf16 bf16x8 __attribute__((ext_vector_type(8)));
typedef __bf16 bf16x4 __attribute__((ext_vector_type(4)));
typedef float  f32x4  __attribute__((ext_vector_type(4)));

#define MFMA16(a, b, c) __builtin_amdgcn_mfma_f32_16x16x32_bf16((a), (b), (c), 0, 0, 0)

// B=2, N=M=2048, QUERY_DIM=CONTEXT_DIM=1024, HEADS=8, DIM_HEAD=64, INNER=512
#define INNER   512
#define DHEAD   64
// SCALE * log2(e): Q pre-scaled so softmax runs in exp2 domain
#define QSCALE  0.18033688f

// direct HBM -> LDS, 16 B per lane; LDS dest = wave-uniform base + lane*16
__device__ __forceinline__ void g2l(const bf16_t* g, bf16_t* l) {
  __builtin_amdgcn_global_load_lds(
      (const __attribute__((address_space(1))) unsigned int*)g,
      (__attribute__((address_space(3))) unsigned int*)l, 16, 0, 0);
}

// ---------- weight transpose+convert only (x/ctx now consumed as fp32) ----------
__global__ __launch_bounds__(256) void pre_k(const float* __restrict__ Wq,
                                             const float* __restrict__ Wk,
                                             const float* __restrict__ Wv,
                                             const float* __restrict__ Wo,
                                             bf16_t* __restrict__ WqT,
                                             bf16_t* __restrict__ WkT,
                                             bf16_t* __restrict__ WvT,
                                             bf16_t* __restrict__ WoT) {
  __shared__ float tile[64][65];
  int t = blockIdx.x;
  int z = t >> 7, bid = t & 127;
  const float* W; bf16_t* WT; int K, N;
  if (z == 0)      { W = Wq; WT = WqT; K = 1024; N = 512; }
  else if (z == 1) { W = Wk; WT = WkT; K = 1024; N = 512; }
  else if (z == 2) { W = Wv; WT = WvT; K = 1024; N = 512; }
  else             { W = Wo; WT = WoT; K = 512;  N = 1024; }
  int tK = K >> 6;
  int kt = bid % tK, nt = bid / tK;
  int k0 = kt << 6, n0 = nt << 6;
  for (int idx = threadIdx.x; idx < 4096; idx += 256) {
    int r = idx >> 6, c = idx & 63;
    tile[r][c] = W[(size_t)(k0 + r) * N + n0 + c];
  }
  __syncthreads();
  for (int idx = threadIdx.x; idx < 4096; idx += 256) {
    int r = idx >> 6, c = idx & 63;
    WT[(size_t)(n0 + r) * K + k0 + c] = (bf16_t)tile[c][r];
  }
}

// ---------- QKV GEMM: A fp32 (in-register cvt), B bf16 via g2l, BK=32 ----------
// LDS tiles 128x32 bf16 unpadded; 16B chunks XOR-swizzled: phys = log ^ ((row>>1)&3)
// mode 0: bf16 out with scale; mode 2: scatter to Vt[bh][d][key].
__global__ __launch_bounds__(256, 2) void gemm_qkv_k(const float* __restrict__ x,
                                                     const float* __restrict__ ctx,
                                                     const bf16_t* __restrict__ WqT,
                                                     const bf16_t* __restrict__ WkT,
                                                     const bf16_t* __restrict__ WvT,
                                                     bf16_t* __restrict__ Qb,
                                                     bf16_t* __restrict__ Kb,
                                                     bf16_t* __restrict__ Vt) {
  const int z = blockIdx.z;
  const float*  A  = (z == 0) ? x   : ctx;
  const bf16_t* Bt = (z == 0) ? WqT : (z == 1) ? WkT : WvT;
  bf16_t* C        = (z == 0) ? Qb  : (z == 1) ? Kb  : Vt;
  const int mode   = (z == 2) ? 2 : 0;
  const float scale = (z == 0) ? QSCALE : 1.0f;
  const int K = 1024, K4 = 256, row0 = blockIdx.y * 128, n0 = blockIdx.x * 128;

  __shared__ bf16_t As[128 * 32];
  __shared__ bf16_t Bs[128 * 32];
  const int tid = threadIdx.x;
  const int w = tid >> 6, lane = tid & 63, quad = lane >> 4, l16 = lane & 15;

  // ---- A staging map (fp32): thread t covers float4 slots lin = t + i*256,
  // r = (t>>3)+32i, c = t&7 (float4 col). LDS chunk(16B)=2 float4s.
  const int ar = tid >> 3;             // + 32*i
  const int ac = tid & 7;              // float4 col, constant
  const float4* agp = (const float4*)A + (size_t)(row0 + ar) * K4 + ac;
  // LDS elem addr: r*32 + phys*8 + (c&1)*4, phys = (c>>1) ^ ((r>>1)&3)
  const int aoff0 = (ac & 1) * 4;
  // ---- B staging map (bf16 g2l): rows w*32+(lane>>2), phys chunk lane&3
  const int srow = lane >> 2;
  const int logc = (lane & 3) ^ ((lane >> 3) & 3);
  const bf16_t* gbw = Bt + (size_t)(n0 + w * 32 + srow) * K + logc * 8;
  bf16_t* lB = Bs + w * 1024;

  f32x4 acc[4][4];
#pragma unroll
  for (int i = 0; i < 4; ++i)
#pragma unroll
    for (int j = 0; j < 4; ++j) acc[i][j] = f32x4{0.f, 0.f, 0.f, 0.f};

  const int mrow = (w & 1) << 6, ncol = (w >> 1) << 6;
  const int rphys = (quad ^ ((l16 >> 1) & 3)) << 3;

  float4 apre[4];
#pragma unroll
  for (int i = 0; i < 4; ++i) apre[i] = agp[(size_t)(32 * i) * K4];

  for (int kc = 0; kc < 32; ++kc) {
    __syncthreads();
#pragma unroll
    for (int i = 0; i < 4; ++i) {
      int r = ar + 32 * i;
      int phys = (ac >> 1) ^ ((r >> 1) & 3);
      bf16x4 v = { (bf16_t)apre[i].x, (bf16_t)apre[i].y,
                   (bf16_t)apre[i].z, (bf16_t)apre[i].w };
      *(bf16x4*)&As[r * 32 + phys * 8 + aoff0] = v;
    }
    g2l(gbw + kc * 32,                  lB);
    g2l(gbw + (size_t)16 * K + kc * 32, lB + 512);
    __syncthreads();
    if (kc + 1 < 32) {
#pragma unroll
      for (int i = 0; i < 4; ++i)
        apre[i] = agp[(size_t)(32 * i) * K4 + (kc + 1) * 8];
    }
    bf16x8 af[4], bfr[4];
#pragma unroll
    for (int i = 0; i < 4; ++i)
      af[i] = *(const bf16x8*)&As[(mrow + i * 16 + l16) * 32 + rphys];
#pragma unroll
    for (int j = 0; j < 4; ++j)
      bfr[j] = *(const bf16x8*)&Bs[(ncol + j * 16 + l16) * 32 + rphys];
#pragma unroll
    for (int i = 0; i < 4; ++i)
#pragma unroll
      for (int j = 0; j < 4; ++j)
        acc[i][j] = MFMA16(af[i], bfr[j], acc[i][j]);
  }

  // epilogue: C/D layout col=l16, row=quad*4+reg
#pragma unroll
  for (int i = 0; i < 4; ++i) {
    int row = row0 + mrow + i * 16 + quad * 4;
#pragma unroll
    for (int j = 0; j < 4; ++j) {
      int col = n0 + ncol + j * 16 + l16;
      if (mode == 2) {
        int bb = row >> 11, key = row & 2047;
        int hh = col >> 6,  d   = col & 63;
        bf16x4 v = { (bf16_t)acc[i][j][0], (bf16_t)acc[i][j][1],
                     (bf16_t)acc[i][j][2], (bf16_t)acc[i][j][3] };
        *(bf16x4*)&C[((size_t)((bb * 8 + hh) * 64 + d)) * 2048 + key] = v;
      } else {
#pragma unroll
        for (int r = 0; r < 4; ++r)
          C[(size_t)(row + r) * 512 + col] = (bf16_t)(acc[i][j][r] * scale);
      }
    }
  }
}

// ---------- output GEMM: A=AO bf16, B=WoT bf16, both g2l; f32 out + bias ----------
__global__ __launch_bounds__(256, 2) void gemm_out_k(const bf16_t* __restrict__ AO,
                                                     const bf16_t* __restrict__ WoT,
                                                     const float* __restrict__ bo,
                                                     float* __restrict__ out) {
  const int K = 512, N = 1024, row0 = blockIdx.y * 128, n0 = blockIdx.x * 128;
  __shared__ bf16_t As[128 * 32];
  __shared__ bf16_t Bs[128 * 32];
  const int tid = threadIdx.x;
  const int w = tid >> 6, lane = tid & 63, quad = lane >> 4, l16 = lane & 15;

  const int srow = lane >> 2;
  const int logc = (lane & 3) ^ ((lane >> 3) & 3);
  const bf16_t* gaw = AO  + (size_t)(row0 + w * 32 + srow) * K + logc * 8;
  const bf16_t* gbw = WoT + (size_t)(n0   + w * 32 + srow) * K + logc * 8;
  bf16_t* lA = As + w * 1024;
  bf16_t* lB = Bs + w * 1024;

  f32x4 acc[4][4];
#pragma unroll
  for (int i = 0; i < 4; ++i)
#pragma unroll
    for (int j = 0; j < 4; ++j) acc[i][j] = f32x4{0.f, 0.f, 0.f, 0.f};

  const int mrow = (w & 1) << 6, ncol = (w >> 1) << 6;
  const int rphys = (quad ^ ((l16 >> 1) & 3)) << 3;

  for (int kc = 0; kc < 16; ++kc) {
    __syncthreads();
    g2l(gaw + kc * 32,                  lA);
    g2l(gaw + (size_t)16 * K + kc * 32, lA + 512);
    g2l(gbw + kc * 32,                  lB);
    g2l(gbw + (size_t)16 * K + kc * 32, lB + 512);
    __syncthreads();
    bf16x8 af[4], bfr[4];
#pragma unroll
    for (int i = 0; i < 4; ++i)
      af[i] = *(const bf16x8*)&As[(mrow + i * 16 + l16) * 32 + rphys];
#pragma unroll
    for (int j = 0; j < 4; ++j)
      bfr[j] = *(const bf16x8*)&Bs[(ncol + j * 16 + l16) * 32 + rphys];
#pragma unroll
    for (int i = 0; i < 4; ++i)
#pragma unroll
      for (int j = 0; j < 4; ++j)
        acc[i][j] = MFMA16(af[i], bfr[j], acc[i][j]);
  }
#pragma unroll
  for (int i = 0; i < 4; ++i) {
    int row = row0 + mrow + i * 16 + quad * 4;
#pragma unroll
    for (int j = 0; j < 4; ++j) {
      int col = n0 + ncol + j * 16 + l16;
#pragma unroll
      for (int r = 0; r < 4; ++r)
        out[(size_t)(row + r) * N + col] = acc[i][j][r] + bo[col];
    }
  }
}

// ---------- flash attention: transposed-S, pipelined staging (unchanged R4) ----------
__global__ __launch_bounds__(256, 2) void attn_k(const bf16_t* __restrict__ Qb,
                                                 const bf16_t* __restrict__ Kb,
                                                 const bf16_t* __restrict__ Vt,
                                                 bf16_t* __restrict__ AO) {
  const int tid = threadIdx.x;
  const int w = tid >> 6, lane = tid & 63, quad = lane >> 4, l16 = lane & 15;
  const int qt = blockIdx.x;        // 0..31
  const int bh = blockIdx.y;        // 0..15
  const int b = bh >> 3, h = bh & 7;

  __shared__ bf16_t Ks[2 * 128 * 64];  // [buf][key][d] rows 128 B, swizzle r&7
  __shared__ bf16_t Vs[64 * 128];      // [d][key]      rows 256 B, swizzle r&15
  __shared__ bf16_t Ps[64 * 136];      // [q][key]      padded, wave-private rows

  const int qrow = b * 2048 + qt * 64 + w * 16 + l16;
  const bf16_t* qptr = Qb + (size_t)qrow * INNER + h * DHEAD;
  bf16x8 bq[2];
  bq[0] = *(const bf16x8*)(qptr + quad * 8);
  bq[1] = *(const bf16x8*)(qptr + 32 + quad * 8);

  f32x4 o[4];
#pragma unroll
  for (int dt = 0; dt < 4; ++dt) o[dt] = f32x4{0.f, 0.f, 0.f, 0.f};
  float m_s = -__builtin_inff(), l_s = 0.f;

  const bf16_t* kbase  = Kb + ((size_t)b * 2048) * INNER + h * DHEAD;
  const bf16_t* vtbase = Vt + ((size_t)bh * 64) * 2048;

  const int krow = lane >> 3;
  const int kcol = ((lane & 7) ^ (lane >> 3)) << 3;
  const int vrow = lane >> 4;

#pragma unroll
  for (int p = 0; p < 4; ++p)
    g2l(kbase + (size_t)(w * 32 + p * 8 + krow) * INNER + kcol,
        &Ks[w * 2048 + p * 512]);

  for (int kt = 0; kt < 16; ++kt) {
    const int cur = (kt & 1) * 8192, nxt = ((kt + 1) & 1) * 8192;
    __syncthreads();
    if (kt < 16 - 1) {
#pragma unroll
      for (int p = 0; p < 4; ++p)
        g2l(kbase + (size_t)((kt + 1) * 128 + w * 32 + p * 8 + krow) * INNER + kcol,
            &Ks[nxt + w * 2048 + p * 512]);
    }
#pragma unroll
    for (int p = 0; p < 4; ++p) {
      int vlog = ((lane & 15) ^ ((p * 4 + vrow) & 15)) << 3;
      g2l(vtbase + (size_t)(w * 16 + p * 4 + vrow) * 2048 + kt * 128 + vlog,
          &Vs[w * 2048 + p * 512]);
    }

    f32x4 s[8];
#pragma unroll
    for (int jt = 0; jt < 8; ++jt) s[jt] = f32x4{0.f, 0.f, 0.f, 0.f};
#pragma unroll
    for (int jt = 0; jt < 8; ++jt) {
#pragma unroll
      for (int ks = 0; ks < 2; ++ks) {
        int phys = ((ks * 4 + quad) ^ (l16 & 7)) << 3;
        bf16x8 ak = *(const bf16x8*)&Ks[cur + (jt * 16 + l16) * 64 + phys];
        s[jt] = MFMA16(ak, bq[ks], s[jt]);
      }
    }

    float mx = -__builtin_inff();
#pragma unroll
    for (int jt = 0; jt < 8; ++jt) {
      float a = fmaxf(fmaxf(s[jt][0], s[jt][1]), fmaxf(s[jt][2], s[jt][3]));
      mx = fmaxf(mx, a);
    }
    mx = fmaxf(mx, __shfl_xor(mx, 16, 64));
    mx = fmaxf(mx, __shfl_xor(mx, 32, 64));
    float mnew = fmaxf(m_s, mx);
    float alpha = __builtin_amdgcn_exp2f(m_s - mnew);
    float rs = 0.f;
#pragma unroll
    for (int jt = 0; jt < 8; ++jt) {
#pragma unroll
      for (int r = 0; r < 4; ++r) {
        float p = __builtin_amdgcn_exp2f(s[jt][r] - mnew);
        s[jt][r] = p;
        rs += p;
      }
    }
    rs += __shfl_xor(rs, 16, 64);
    rs += __shfl_xor(rs, 32, 64);
    l_s = l_s * alpha + rs;
    m_s = mnew;
#pragma unroll
    for (int dt = 0; dt < 4; ++dt) o[dt] *= alpha;

#pragma unroll
    for (int jt = 0; jt < 8; ++jt) {
      bf16x4 pk = { (bf16_t)s[jt][0], (bf16_t)s[jt][1],
                    (bf16_t)s[jt][2], (bf16_t)s[jt][3] };
      *(bf16x4*)&Ps[(w * 16 + l16) * 136 + jt * 16 + quad * 4] = pk;
    }

    __syncthreads();

#pragma unroll
    for (int kc = 0; kc < 4; ++kc) {
      bf16x8 bp = *(const bf16x8*)&Ps[(w * 16 + l16) * 136 + kc * 32 + quad * 8];
#pragma unroll
      for (int dt = 0; dt < 4; ++dt) {
        int phys = ((kc * 4 + quad) ^ l16) << 3;
        bf16x8 av = *(const bf16x8*)&Vs[(dt * 16 + l16) * 128 + phys];
        o[dt] = MFMA16(av, bp, o[dt]);
      }
    }
  }

  float inv = 1.0f / l_s;
#pragma unroll
  for (int dt = 0; dt < 4; ++dt) {
    bf16x4 ov = { (bf16_t)(o[dt][0] * inv), (bf16_t)(o[dt][1] * inv),
                  (bf16_t)(o[dt][2] * inv), (bf16_t)(o[dt][3] * inv) };
    *(bf16x4*)&Ps[(w * 16 + l16) * 136 + dt * 16 + quad * 4] = ov;
  }
  __syncthreads();
  {
    int sr = tid >> 2, sc = (tid & 3) << 4;
    int4 r0 = *(const int4*)&Ps[sr * 136 + sc];
    int4 r1 = *(const int4*)&Ps[sr * 136 + sc + 8];
    bf16_t* aout = AO + ((size_t)(b * 2048 + qt * 64 + sr)) * INNER + h * DHEAD + sc;
    *(int4*)aout       = r0;
    *(int4*)(aout + 8) = r1;
  }
}

// ---------- launch ----------
extern "C" void kernel_launch(void* const* d_in, const int* in_sizes, int n_in,
                              void* d_out, int out_size, void* d_ws, size_t ws_size,
                              hipStream_t stream) {
  const float* x   = (const float*)d_in[0];
  const float* ctx = (const float*)d_in[1];
  const float* Wq  = (const float*)d_in[2];
  const float* Wk  = (const float*)d_in[3];
  const float* Wv  = (const float*)d_in[4];
  const float* Wo  = (const float*)d_in[5];
  const float* bo  = (const float*)d_in[6];
  float* out = (float*)d_out;

  char* ws = (char*)d_ws;
  const size_t MB = 1048576;
  bf16_t* WqT = (bf16_t*)(ws + 0 * MB);    //  1 MB  [512][1024]
  bf16_t* WkT = (bf16_t*)(ws + 1 * MB);    //  1 MB
  bf16_t* WvT = (bf16_t*)(ws + 2 * MB);    //  1 MB
  bf16_t* WoT = (bf16_t*)(ws + 3 * MB);    //  1 MB  [1024][512]
  bf16_t* Qb  = (bf16_t*)(ws + 4 * MB);    //  4 MB  [4096][512] (pre-scaled)
  bf16_t* Kb  = (bf16_t*)(ws + 8 * MB);    //  4 MB  [4096][512]
  bf16_t* Vt  = (bf16_t*)(ws + 12 * MB);   //  4 MB  [16][64][2048]
  bf16_t* AO  = (bf16_t*)(ws + 16 * MB);   //  4 MB  [4096][512]

  pre_k<<<512, 256, 0, stream>>>(Wq, Wk, Wv, Wo, WqT, WkT, WvT, WoT);
  gemm_qkv_k<<<dim3(4, 32, 3), 256, 0, stream>>>(x, ctx, WqT, WkT, WvT, Qb, Kb, Vt);
  attn_k<<<dim3(32, 16), 256, 0, stream>>>(Qb, Kb, Vt, AO);
  gemm_out_k<<<dim3(8, 32), 256, 0, stream>>>(AO, WoT, bo, out);
}

// Round 6
// 165.483 us; speedup vs baseline: 1.0829x; 1.0829x over previous
//
#include <hip/hip_runtime.h>
#include <math.h>

// ---------- types ----------
typedef __bf16 bf16_t;
typedef __bf16 bf16x8 __attribute__((ext_vector_type(8)));
typedef __bf16 bf16x4 __attribute__((ext_vector_type(4)));
typedef float  f32x4  __attribute__((ext_vector_type(4)));

#define MFMA16(a, b, c) __builtin_amdgcn_mfma_f32_16x16x32_bf16((a), (b), (c), 0, 0, 0)

// B=2, N=M=2048, QUERY_DIM=CONTEXT_DIM=1024, HEADS=8, DIM_HEAD=64, INNER=512
#define INNER   512
#define DHEAD   64
// SCALE * log2(e): Q pre-scaled so softmax runs in exp2 domain
#define QSCALE  0.18033688f

// direct HBM -> LDS, 16 B per lane; LDS dest = wave-uniform base + lane*16
__device__ __forceinline__ void g2l(const bf16_t* g, bf16_t* l) {
  __builtin_amdgcn_global_load_lds(
      (const __attribute__((address_space(1))) unsigned int*)g,
      (__attribute__((address_space(3))) unsigned int*)l, 16, 0, 0);
}

// ---------- fused preprocessing ----------
// bx < 8192 : fp32->bf16 convert (x: 0..4095, ctx: 4096..8191)
// bx >= 8192: weight transpose+convert, 4 matrices x 128 tiles
__global__ __launch_bounds__(256) void pre_k(const float* __restrict__ x,
                                             const float* __restrict__ ctx,
                                             const float* __restrict__ Wq,
                                             const float* __restrict__ Wk,
                                             const float* __restrict__ Wv,
                                             const float* __restrict__ Wo,
                                             bf16_t* __restrict__ xb,
                                             bf16_t* __restrict__ cb,
                                             bf16_t* __restrict__ WqT,
                                             bf16_t* __restrict__ WkT,
                                             bf16_t* __restrict__ WvT,
                                             bf16_t* __restrict__ WoT) {
  __shared__ float tile[64][65];
  int bx = blockIdx.x;
  if (bx < 8192) {
    const float* in = (bx >= 4096) ? ctx : x;
    bf16_t* out     = (bx >= 4096) ? cb  : xb;
    int i = (bx & 4095) * 256 + threadIdx.x;
    float4 f = ((const float4*)in)[i];
    bf16x4 v = { (bf16_t)f.x, (bf16_t)f.y, (bf16_t)f.z, (bf16_t)f.w };
    ((bf16x4*)out)[i] = v;
    return;
  }
  int t = bx - 8192;
  int z = t >> 7, bid = t & 127;
  const float* W; bf16_t* WT; int K, N;
  if (z == 0)      { W = Wq; WT = WqT; K = 1024; N = 512; }
  else if (z == 1) { W = Wk; WT = WkT; K = 1024; N = 512; }
  else if (z == 2) { W = Wv; WT = WvT; K = 1024; N = 512; }
  else             { W = Wo; WT = WoT; K = 512;  N = 1024; }
  int tK = K >> 6;
  int kt = bid % tK, nt = bid / tK;
  int k0 = kt << 6, n0 = nt << 6;
  for (int idx = threadIdx.x; idx < 4096; idx += 256) {
    int r = idx >> 6, c = idx & 63;
    tile[r][c] = W[(size_t)(k0 + r) * N + n0 + c];
  }
  __syncthreads();
  for (int idx = threadIdx.x; idx < 4096; idx += 256) {
    int r = idx >> 6, c = idx & 63;
    WT[(size_t)(n0 + r) * K + k0 + c] = (bf16_t)tile[c][r];
  }
}

// ---------- 128x128 GEMM, BK=64, double-buffered g2l with early issue ----------
// LDS tiles 128x64 bf16 (128-B rows), XOR-swizzled 16-B chunks: phys = log ^ (row&7).
// One barrier per iteration: publish buf[cur], issue tile kc+1 into buf[nxt],
// compute 32 MFMA on buf[cur] while loads fly (issue-early / drain-late).
// mode 0: bf16 out * scale; mode 1: f32 out + bias; mode 2: scatter to Vt.
__device__ __forceinline__ void gemm128(const bf16_t* __restrict__ A,
                                        const bf16_t* __restrict__ Bt,
                                        int K, int N, int row0, int n0,
                                        int mode, float scale,
                                        bf16_t* __restrict__ Cb,
                                        float* __restrict__ Cf,
                                        const float* __restrict__ bias) {
  __shared__ bf16_t As[2 * 128 * 64];   // 32 KB
  __shared__ bf16_t Bs[2 * 128 * 64];   // 32 KB
  const int tid = threadIdx.x;
  const int w = tid >> 6, lane = tid & 63, quad = lane >> 4, l16 = lane & 15;

  // staging: wave w covers rows [w*32, w*32+32) of A and B; per g2l p: rows
  // w*32+p*8+(lane>>3), phys chunk lane&7 -> global logical chunk (lane&7)^(lane>>3)
  const int sr8  = lane >> 3;                    // 0..7
  const int slog = ((lane & 7) ^ sr8) << 3;      // logical col (elems)
  const bf16_t* ga = A  + (size_t)(row0 + w * 32 + sr8) * K + slog;
  const bf16_t* gb = Bt + (size_t)(n0   + w * 32 + sr8) * K + slog;
  bf16_t* lA = As + w * 2048;                    // + buf*8192 + p*512
  bf16_t* lB = Bs + w * 2048;

  f32x4 acc[4][4];
#pragma unroll
  for (int i = 0; i < 4; ++i)
#pragma unroll
    for (int j = 0; j < 4; ++j) acc[i][j] = f32x4{0.f, 0.f, 0.f, 0.f};

  const int mrow = (w & 1) << 6, ncol = (w >> 1) << 6;
  const int KT = K >> 6;

  // prologue: tile 0 -> buf 0
#pragma unroll
  for (int p = 0; p < 4; ++p) {
    g2l(ga + (size_t)(p * 8) * K, lA + p * 512);
    g2l(gb + (size_t)(p * 8) * K, lB + p * 512);
  }

  for (int kc = 0; kc < KT; ++kc) {
    const int cur = (kc & 1) * 8192, nxt = ((kc + 1) & 1) * 8192;
    __syncthreads();              // drains tile-kc loads; publishes buf[cur]
    if (kc + 1 < KT) {            // issue tile kc+1 early; MFMA hides flight
      const int k0 = (kc + 1) * 64;
#pragma unroll
      for (int p = 0; p < 4; ++p) {
        g2l(ga + (size_t)(p * 8) * K + k0, lA + nxt + p * 512);
        g2l(gb + (size_t)(p * 8) * K + k0, lB + nxt + p * 512);
      }
    }
#pragma unroll
    for (int ks = 0; ks < 2; ++ks) {
      const int phys = ((ks * 4 + quad) ^ (l16 & 7)) << 3;
      bf16x8 af[4], bfr[4];
#pragma unroll
      for (int i = 0; i < 4; ++i)
        af[i] = *(const bf16x8*)&As[cur + (mrow + i * 16 + l16) * 64 + phys];
#pragma unroll
      for (int j = 0; j < 4; ++j)
        bfr[j] = *(const bf16x8*)&Bs[cur + (ncol + j * 16 + l16) * 64 + phys];
#pragma unroll
      for (int i = 0; i < 4; ++i)
#pragma unroll
        for (int j = 0; j < 4; ++j)
          acc[i][j] = MFMA16(af[i], bfr[j], acc[i][j]);
    }
  }

  // epilogue: C/D layout col=l16, row=quad*4+reg
#pragma unroll
  for (int i = 0; i < 4; ++i) {
    int row = row0 + mrow + i * 16 + quad * 4;
#pragma unroll
    for (int j = 0; j < 4; ++j) {
      int col = n0 + ncol + j * 16 + l16;
      if (mode == 2) {
        // scatter to Vt[bh=b*8+h][d][key]: row -> (b,key), col -> (h,d)
        int bb = row >> 11, key = row & 2047;
        int hh = col >> 6,  d   = col & 63;
        bf16x4 v = { (bf16_t)acc[i][j][0], (bf16_t)acc[i][j][1],
                     (bf16_t)acc[i][j][2], (bf16_t)acc[i][j][3] };
        *(bf16x4*)&Cb[((size_t)((bb * 8 + hh) * 64 + d)) * 2048 + key] = v;
      } else {
#pragma unroll
        for (int r = 0; r < 4; ++r) {
          if (mode == 1) Cf[(size_t)(row + r) * N + col] = acc[i][j][r] + bias[col];
          else           Cb[(size_t)(row + r) * N + col] = (bf16_t)(acc[i][j][r] * scale);
        }
      }
    }
  }
}

__global__ __launch_bounds__(256, 2) void gemm_qkv_k(const bf16_t* __restrict__ xb,
                                                     const bf16_t* __restrict__ cb,
                                                     const bf16_t* __restrict__ WqT,
                                                     const bf16_t* __restrict__ WkT,
                                                     const bf16_t* __restrict__ WvT,
                                                     bf16_t* __restrict__ Qb,
                                                     bf16_t* __restrict__ Kb,
                                                     bf16_t* __restrict__ Vt) {
  int z = blockIdx.z;
  const bf16_t* A  = (z == 0) ? xb  : cb;
  const bf16_t* Bt = (z == 0) ? WqT : (z == 1) ? WkT : WvT;
  bf16_t* C        = (z == 0) ? Qb  : (z == 1) ? Kb  : Vt;
  int mode         = (z == 2) ? 2 : 0;
  float scale      = (z == 0) ? QSCALE : 1.0f;
  gemm128(A, Bt, 1024, 512, blockIdx.y * 128, blockIdx.x * 128, mode, scale,
          C, nullptr, nullptr);
}

__global__ __launch_bounds__(256, 2) void gemm_out_k(const bf16_t* __restrict__ AO,
                                                     const bf16_t* __restrict__ WoT,
                                                     const float* __restrict__ bo,
                                                     float* __restrict__ out) {
  gemm128(AO, WoT, 512, 1024, blockIdx.y * 128, blockIdx.x * 128, 1, 1.0f,
          nullptr, out, bo);
}

// ---------- flash attention: transposed-S, pipelined staging (unchanged) ----------
__global__ __launch_bounds__(256, 2) void attn_k(const bf16_t* __restrict__ Qb,
                                                 const bf16_t* __restrict__ Kb,
                                                 const bf16_t* __restrict__ Vt,
                                                 bf16_t* __restrict__ AO) {
  const int tid = threadIdx.x;
  const int w = tid >> 6, lane = tid & 63, quad = lane >> 4, l16 = lane & 15;
  const int qt = blockIdx.x;        // 0..31
  const int bh = blockIdx.y;        // 0..15
  const int b = bh >> 3, h = bh & 7;

  __shared__ bf16_t Ks[2 * 128 * 64];  // [buf][key][d] rows 128 B, swizzle r&7
  __shared__ bf16_t Vs[64 * 128];      // [d][key]      rows 256 B, swizzle r&15
  __shared__ bf16_t Ps[64 * 136];      // [q][key]      padded, wave-private rows

  const int qrow = b * 2048 + qt * 64 + w * 16 + l16;
  const bf16_t* qptr = Qb + (size_t)qrow * INNER + h * DHEAD;
  bf16x8 bq[2];
  bq[0] = *(const bf16x8*)(qptr + quad * 8);
  bq[1] = *(const bf16x8*)(qptr + 32 + quad * 8);

  f32x4 o[4];
#pragma unroll
  for (int dt = 0; dt < 4; ++dt) o[dt] = f32x4{0.f, 0.f, 0.f, 0.f};
  float m_s = -__builtin_inff(), l_s = 0.f;

  const bf16_t* kbase  = Kb + ((size_t)b * 2048) * INNER + h * DHEAD;
  const bf16_t* vtbase = Vt + ((size_t)bh * 64) * 2048;

  const int krow = lane >> 3;
  const int kcol = ((lane & 7) ^ (lane >> 3)) << 3;
  const int vrow = lane >> 4;

#pragma unroll
  for (int p = 0; p < 4; ++p)
    g2l(kbase + (size_t)(w * 32 + p * 8 + krow) * INNER + kcol,
        &Ks[w * 2048 + p * 512]);

  for (int kt = 0; kt < 16; ++kt) {
    const int cur = (kt & 1) * 8192, nxt = ((kt + 1) & 1) * 8192;
    __syncthreads();
    if (kt < 16 - 1) {
#pragma unroll
      for (int p = 0; p < 4; ++p)
        g2l(kbase + (size_t)((kt + 1) * 128 + w * 32 + p * 8 + krow) * INNER + kcol,
            &Ks[nxt + w * 2048 + p * 512]);
    }
#pragma unroll
    for (int p = 0; p < 4; ++p) {
      int vlog = ((lane & 15) ^ ((p * 4 + vrow) & 15)) << 3;
      g2l(vtbase + (size_t)(w * 16 + p * 4 + vrow) * 2048 + kt * 128 + vlog,
          &Vs[w * 2048 + p * 512]);
    }

    f32x4 s[8];
#pragma unroll
    for (int jt = 0; jt < 8; ++jt) s[jt] = f32x4{0.f, 0.f, 0.f, 0.f};
#pragma unroll
    for (int jt = 0; jt < 8; ++jt) {
#pragma unroll
      for (int ks = 0; ks < 2; ++ks) {
        int phys = ((ks * 4 + quad) ^ (l16 & 7)) << 3;
        bf16x8 ak = *(const bf16x8*)&Ks[cur + (jt * 16 + l16) * 64 + phys];
        s[jt] = MFMA16(ak, bq[ks], s[jt]);
      }
    }

    float mx = -__builtin_inff();
#pragma unroll
    for (int jt = 0; jt < 8; ++jt) {
      float a = fmaxf(fmaxf(s[jt][0], s[jt][1]), fmaxf(s[jt][2], s[jt][3]));
      mx = fmaxf(mx, a);
    }
    mx = fmaxf(mx, __shfl_xor(mx, 16, 64));
    mx = fmaxf(mx, __shfl_xor(mx, 32, 64));
    float mnew = fmaxf(m_s, mx);
    float alpha = __builtin_amdgcn_exp2f(m_s - mnew);
    float rs = 0.f;
#pragma unroll
    for (int jt = 0; jt < 8; ++jt) {
#pragma unroll
      for (int r = 0; r < 4; ++r) {
        float p = __builtin_amdgcn_exp2f(s[jt][r] - mnew);
        s[jt][r] = p;
        rs += p;
      }
    }
    rs += __shfl_xor(rs, 16, 64);
    rs += __shfl_xor(rs, 32, 64);
    l_s = l_s * alpha + rs;
    m_s = mnew;
#pragma unroll
    for (int dt = 0; dt < 4; ++dt) o[dt] *= alpha;

#pragma unroll
    for (int jt = 0; jt < 8; ++jt) {
      bf16x4 pk = { (bf16_t)s[jt][0], (bf16_t)s[jt][1],
                    (bf16_t)s[jt][2], (bf16_t)s[jt][3] };
      *(bf16x4*)&Ps[(w * 16 + l16) * 136 + jt * 16 + quad * 4] = pk;
    }

    __syncthreads();

#pragma unroll
    for (int kc = 0; kc < 4; ++kc) {
      bf16x8 bp = *(const bf16x8*)&Ps[(w * 16 + l16) * 136 + kc * 32 + quad * 8];
#pragma unroll
      for (int dt = 0; dt < 4; ++dt) {
        int phys = ((kc * 4 + quad) ^ l16) << 3;
        bf16x8 av = *(const bf16x8*)&Vs[(dt * 16 + l16) * 128 + phys];
        o[dt] = MFMA16(av, bp, o[dt]);
      }
    }
  }

  float inv = 1.0f / l_s;
#pragma unroll
  for (int dt = 0; dt < 4; ++dt) {
    bf16x4 ov = { (bf16_t)(o[dt][0] * inv), (bf16_t)(o[dt][1] * inv),
                  (bf16_t)(o[dt][2] * inv), (bf16_t)(o[dt][3] * inv) };
    *(bf16x4*)&Ps[(w * 16 + l16) * 136 + dt * 16 + quad * 4] = ov;
  }
  __syncthreads();
  {
    int sr = tid >> 2, sc = (tid & 3) << 4;
    int4 r0 = *(const int4*)&Ps[sr * 136 + sc];
    int4 r1 = *(const int4*)&Ps[sr * 136 + sc + 8];
    bf16_t* aout = AO + ((size_t)(b * 2048 + qt * 64 + sr)) * INNER + h * DHEAD + sc;
    *(int4*)aout       = r0;
    *(int4*)(aout + 8) = r1;
  }
}

// ---------- launch ----------
extern "C" void kernel_launch(void* const* d_in, const int* in_sizes, int n_in,
                              void* d_out, int out_size, void* d_ws, size_t ws_size,
                              hipStream_t stream) {
  const float* x   = (const float*)d_in[0];
  const float* ctx = (const float*)d_in[1];
  const float* Wq  = (const float*)d_in[2];
  const float* Wk  = (const float*)d_in[3];
  const float* Wv  = (const float*)d_in[4];
  const float* Wo  = (const float*)d_in[5];
  const float* bo  = (const float*)d_in[6];
  float* out = (float*)d_out;

  char* ws = (char*)d_ws;
  const size_t MB = 1048576;
  bf16_t* xb  = (bf16_t*)(ws + 0 * MB);    //  8 MB  [4096][1024]
  bf16_t* cb  = (bf16_t*)(ws + 8 * MB);    //  8 MB  [4096][1024]
  bf16_t* WqT = (bf16_t*)(ws + 16 * MB);   //  1 MB  [512][1024]
  bf16_t* WkT = (bf16_t*)(ws + 17 * MB);   //  1 MB
  bf16_t* WvT = (bf16_t*)(ws + 18 * MB);   //  1 MB
  bf16_t* WoT = (bf16_t*)(ws + 19 * MB);   //  1 MB  [1024][512]
  bf16_t* Qb  = (bf16_t*)(ws + 20 * MB);   //  4 MB  [4096][512] (pre-scaled)
  bf16_t* Kb  = (bf16_t*)(ws + 24 * MB);   //  4 MB  [4096][512]
  bf16_t* Vt  = (bf16_t*)(ws + 28 * MB);   //  4 MB  [16][64][2048]
  bf16_t* AO  = (bf16_t*)(ws + 32 * MB);   //  4 MB  [4096][512]

  pre_k<<<8704, 256, 0, stream>>>(x, ctx, Wq, Wk, Wv, Wo, xb, cb, WqT, WkT, WvT, WoT);
  gemm_qkv_k<<<dim3(4, 32, 3), 256, 0, stream>>>(xb, cb, WqT, WkT, WvT, Qb, Kb, Vt);
  attn_k<<<dim3(32, 16), 256, 0, stream>>>(Qb, Kb, Vt, AO);
  gemm_out_k<<<dim3(8, 32), 256, 0, stream>>>(AO, WoT, bo, out);
}